// Round 6
// baseline (553.689 us; speedup 1.0000x reference)
//
#include <hip/hip_runtime.h>

#define NN 50000
#define NP 50048            // padded rows (multiple of 128)
#define HH 128
#define CC 16
#define RRL 8
#define BB 4
#define EE 800000
#define NT (RRL * NN)       // 400000 (dst,rel) buckets, key = dst*8+rel
#define SCAN_CHUNK 2048
#define NBLK_SCAN ((NT + SCAN_CHUNK - 1) / SCAN_CHUNK)  // 196
#define KBIG 1152           // 8*128 (relations) + 128 (self-loop)

typedef short bf16x8_t __attribute__((ext_vector_type(8)));
typedef float f32x4_t __attribute__((ext_vector_type(4)));

__device__ __forceinline__ unsigned short f2bf(float f) {
  unsigned int x = __float_as_uint(f);
  unsigned int r = x + 0x7fffu + ((x >> 16) & 1u);
  return (unsigned short)(r >> 16);
}
__device__ __forceinline__ float bflo(unsigned int u) { return __uint_as_float(u << 16); }
__device__ __forceinline__ float bfhi(unsigned int u) {
  return __uint_as_float(u & 0xffff0000u);
}
__device__ __forceinline__ void acc8(float* a, uint4 v, float nrm) {
  a[0] = fmaf(nrm, bflo(v.x), a[0]);
  a[1] = fmaf(nrm, bfhi(v.x), a[1]);
  a[2] = fmaf(nrm, bflo(v.y), a[2]);
  a[3] = fmaf(nrm, bfhi(v.y), a[3]);
  a[4] = fmaf(nrm, bflo(v.z), a[4]);
  a[5] = fmaf(nrm, bfhi(v.z), a[5]);
  a[6] = fmaf(nrm, bflo(v.w), a[6]);
  a[7] = fmaf(nrm, bfhi(v.w), a[7]);
}

// ---------------- utility ----------------

__global__ __launch_bounds__(256) void zero_kernel(int* p, int n) {
  int i = blockIdx.x * 256 + threadIdx.x;
  if (i < n) p[i] = 0;
}

// ---------------- counting sort by key = dst*8 + rel ----------------

__global__ __launch_bounds__(256) void hist2_kernel(const int* __restrict__ r,
                                                    const int* __restrict__ dst,
                                                    int* __restrict__ cnt) {
  int e = blockIdx.x * 256 + threadIdx.x;
  if (e < EE) atomicAdd(&cnt[dst[e] * RRL + r[e]], 1);
}

__global__ __launch_bounds__(256) void scanA_kernel(const int* __restrict__ cnt,
                                                    int* __restrict__ off,
                                                    int* __restrict__ partials) {
  __shared__ int sums[256];
  int tid = threadIdx.x;
  int base = blockIdx.x * SCAN_CHUNK + tid * 8;
  int v[8];
  int s = 0;
#pragma unroll
  for (int j = 0; j < 8; ++j) {
    int idx = base + j;
    v[j] = (idx < NT) ? cnt[idx] : 0;
    s += v[j];
  }
  sums[tid] = s;
  __syncthreads();
  for (int o = 1; o < 256; o <<= 1) {
    int t = (tid >= o) ? sums[tid - o] : 0;
    __syncthreads();
    sums[tid] += t;
    __syncthreads();
  }
  int run = sums[tid] - s;
#pragma unroll
  for (int j = 0; j < 8; ++j) {
    int idx = base + j;
    if (idx < NT) off[idx] = run;
    run += v[j];
  }
  if (tid == 255) partials[blockIdx.x] = sums[255];
}

__global__ __launch_bounds__(256) void scanB_kernel(const int* __restrict__ partials,
                                                    int* __restrict__ pexcl) {
  __shared__ int sums[256];
  int tid = threadIdx.x;
  int p = (tid < NBLK_SCAN) ? partials[tid] : 0;
  sums[tid] = p;
  __syncthreads();
  for (int o = 1; o < 256; o <<= 1) {
    int t = (tid >= o) ? sums[tid - o] : 0;
    __syncthreads();
    sums[tid] += t;
    __syncthreads();
  }
  if (tid < NBLK_SCAN) pexcl[tid] = sums[tid] - p;
}

__global__ __launch_bounds__(256) void addC_kernel(int* __restrict__ off,
                                                   const int* __restrict__ pexcl,
                                                   int* __restrict__ cur) {
  int tid = threadIdx.x;
  int add = pexcl[blockIdx.x];
  int base = blockIdx.x * SCAN_CHUNK + tid * 8;
#pragma unroll
  for (int j = 0; j < 8; ++j) {
    int idx = base + j;
    if (idx < NT) {
      int v = off[idx] + add;
      off[idx] = v;
      cur[idx] = v;
    }
  }
  if (blockIdx.x == 0 && tid == 0) off[NT] = EE;
}

// payloads: ep0 = (w0b row index = z*NP + h[src], norm bits)
//           ep1 = (src | z<<24, norm bits)
__global__ __launch_bounds__(256) void scatter2_kernel(
    const int* __restrict__ r, const int* __restrict__ dst, const int* __restrict__ src,
    const int* __restrict__ h, const float* __restrict__ norm, int* __restrict__ cur,
    uint2* __restrict__ ep0, uint2* __restrict__ ep1) {
  int e = blockIdx.x * 256 + threadIdx.x;
  if (e >= EE) return;
  int z = r[e];
  int key = dst[e] * RRL + z;
  int pos = atomicAdd(&cur[key], 1);
  int sv = src[e];
  unsigned int nb = __float_as_uint(norm[e]);
  uint2 a, b;
  a.x = (unsigned)(z * NP + h[sv]);
  a.y = nb;
  b.x = (unsigned)sv | ((unsigned)z << 24);
  b.y = nb;
  ep0[pos] = a;
  ep1[pos] = b;
}

// ---------------- compose weights (bf16) ----------------
// w1big[n][k], k in [0,1024): rel z=k>>7; k in [1024,1152): loop1. Layout row-major [128][1152].
// w2t[z][n16][k128], loop2t[n16][k128].

__global__ __launch_bounds__(256) void compose_small_kernel(
    const float* __restrict__ wcomp1, const float* __restrict__ bases1,
    const float* __restrict__ loop1, const float* __restrict__ wcomp2,
    const float* __restrict__ bases2, const float* __restrict__ loop2,
    unsigned short* __restrict__ w1big, unsigned short* __restrict__ w2t,
    unsigned short* __restrict__ loop2t) {
  int idx = blockIdx.x * 256 + threadIdx.x;
  if (idx < HH * KBIG) {  // w1big[n][k]
    int n = idx / KBIG, k = idx - n * KBIG;
    float a;
    if (k < 1024) {
      int z = k >> 7, kk = k & 127;
      a = 0.f;
#pragma unroll
      for (int b = 0; b < BB; ++b)
        a += wcomp1[z * BB + b] * bases1[((size_t)b * HH + kk) * HH + n];
    } else {
      int kk = k - 1024;
      a = loop1[kk * HH + n];
    }
    w1big[idx] = f2bf(a);
    return;
  }
  int j = idx - HH * KBIG;
  if (j < RRL * CC * HH) {  // w2t[z][n][k]
    int z = j >> 11;
    int rem = j & 2047;
    int n = rem >> 7, k = rem & 127;
    float a = 0.f;
#pragma unroll
    for (int b = 0; b < BB; ++b)
      a += wcomp2[z * BB + b] * bases2[((size_t)b * HH + k) * CC + n];
    w2t[j] = f2bf(a);
    return;
  }
  j -= RRL * CC * HH;
  if (j < CC * HH) {  // loop2t[n][k]
    int n = j >> 7, k = j & 127;
    loop2t[j] = f2bf(loop2[k * CC + n]);
  }
}

// ---------------- w0 bf16 table: w0b[z][m][f] ----------------

__global__ __launch_bounds__(256) void w0b_build_kernel(const float* __restrict__ bases0,
                                                        const float* __restrict__ wcomp0,
                                                        unsigned short* __restrict__ w0b) {
  int idx = blockIdx.x * 256 + threadIdx.x;  // m*32 + c
  int m = idx >> 5, c = idx & 31;
  if (m >= NN) return;
  float4 b0 = ((const float4*)(bases0 + ((size_t)0 * NN + m) * HH))[c];
  float4 b1 = ((const float4*)(bases0 + ((size_t)1 * NN + m) * HH))[c];
  float4 b2 = ((const float4*)(bases0 + ((size_t)2 * NN + m) * HH))[c];
  float4 b3 = ((const float4*)(bases0 + ((size_t)3 * NN + m) * HH))[c];
#pragma unroll
  for (int z = 0; z < RRL; ++z) {
    float c0 = wcomp0[z * BB + 0], c1 = wcomp0[z * BB + 1];
    float c2 = wcomp0[z * BB + 2], c3 = wcomp0[z * BB + 3];
    float vx = c0 * b0.x + c1 * b1.x + c2 * b2.x + c3 * b3.x;
    float vy = c0 * b0.y + c1 * b1.y + c2 * b2.y + c3 * b3.y;
    float vz = c0 * b0.z + c1 * b1.z + c2 * b2.z + c3 * b3.z;
    float vw = c0 * b0.w + c1 * b1.w + c2 * b2.w + c3 * b3.w;
    uint2 pk;
    pk.x = ((unsigned)f2bf(vy) << 16) | f2bf(vx);
    pk.y = ((unsigned)f2bf(vw) << 16) | f2bf(vz);
    ((uint2*)(w0b + ((size_t)z * NP + m) * HH))[c] = pk;
  }
}

// ---------------- layer 0: wave/dst, merged range, 4 slots x 16 lanes, 2x unroll ----------------

__global__ __launch_bounds__(256) void l0_seg_kernel(
    const int* __restrict__ h, const int* __restrict__ off2, const uint2* __restrict__ ep0,
    const unsigned short* __restrict__ w0b, const float* __restrict__ loop0,
    const float* __restrict__ bias0, unsigned short* __restrict__ x1b) {
  int lane = threadIdx.x & 63;
  int n = blockIdx.x * 4 + (threadIdx.x >> 6);
  if (n >= NP) return;
  const int g = lane >> 4;
  const int t = lane & 15;
  float acc[8];
#pragma unroll
  for (int j = 0; j < 8; ++j) acc[j] = 0.f;

  if (n < NN) {
    int beg = off2[n * RRL];
    int end = off2[n * RRL + RRL];
    int i = beg + g;
    uint2 p0 = {0u, 0u}, p1 = {0u, 0u};
    if (i < end) p0 = ep0[i];
    if (i + 4 < end) p1 = ep0[i + 4];
    while (i < end) {
      uint2 q0 = {0u, 0u}, q1 = {0u, 0u};
      if (i + 8 < end) q0 = ep0[i + 8];
      if (i + 12 < end) q1 = ep0[i + 12];
      uint4 va = *(const uint4*)(w0b + (size_t)p0.x * HH + t * 8);
      uint4 vb = *(const uint4*)(w0b + (size_t)p1.x * HH + t * 8);
      float na = __uint_as_float(p0.y), nb = __uint_as_float(p1.y);
      acc8(acc, va, na);
      acc8(acc, vb, nb);
      i += 8;
      p0 = q0;
      p1 = q1;
    }
  }
#pragma unroll
  for (int j = 0; j < 8; ++j) {
    acc[j] += __shfl_xor(acc[j], 16, 64);
    acc[j] += __shfl_xor(acc[j], 32, 64);
  }
  if (g != 0) return;
  uint4 o = {0u, 0u, 0u, 0u};
  if (n < NN) {
    int hn = h[n];
    float4 l0v = ((const float4*)(loop0 + (size_t)hn * HH))[t * 2];
    float4 l1v = ((const float4*)(loop0 + (size_t)hn * HH))[t * 2 + 1];
    float4 b0v = ((const float4*)bias0)[t * 2];
    float4 b1v = ((const float4*)bias0)[t * 2 + 1];
    float e0 = fmaxf(acc[0] + l0v.x + b0v.x, 0.f);
    float e1 = fmaxf(acc[1] + l0v.y + b0v.y, 0.f);
    float e2 = fmaxf(acc[2] + l0v.z + b0v.z, 0.f);
    float e3 = fmaxf(acc[3] + l0v.w + b0v.w, 0.f);
    float e4 = fmaxf(acc[4] + l1v.x + b1v.x, 0.f);
    float e5 = fmaxf(acc[5] + l1v.y + b1v.y, 0.f);
    float e6 = fmaxf(acc[6] + l1v.z + b1v.z, 0.f);
    float e7 = fmaxf(acc[7] + l1v.w + b1v.w, 0.f);
    o.x = ((unsigned)f2bf(e1) << 16) | f2bf(e0);
    o.y = ((unsigned)f2bf(e3) << 16) | f2bf(e2);
    o.z = ((unsigned)f2bf(e5) << 16) | f2bf(e4);
    o.w = ((unsigned)f2bf(e7) << 16) | f2bf(e6);
  }
  *(uint4*)(x1b + (size_t)n * HH + t * 8) = o;
}

// ---------------- layer 1 FUSED: register-direct A-frag aggregation + MFMA ----------------
// Block: 64 dst rows, 4 waves. Wave w owns rows row0+w*16 .. +15, one row per l15 lane.
// Lane (quad,l15) aggregates A[m=l15][k=ks*32+quad*8+j] (ks=0..3) in fp32 regs -> bf16 frag
// -> 32 MFMA vs LDS-staged w1big slice. kb=8 is the self-loop slice (A-frags from x1b).

__global__ __launch_bounds__(256) void l1_fused_kernel(
    const int* __restrict__ off2, const uint2* __restrict__ ep1,
    const unsigned short* __restrict__ x1b, const unsigned short* __restrict__ w1big,
    const float* __restrict__ bias1, unsigned short* __restrict__ x2b) {
  constexpr int LP = 136;
  __shared__ unsigned short Blds[128 * LP];
  const int tid = threadIdx.x;
  const int w = tid >> 6, lane = tid & 63;
  const int quad = lane >> 4, l15 = lane & 15;
  const int row0 = blockIdx.x * 64;
  const int myrow = row0 + w * 16 + l15;

  f32x4_t acc[8];
#pragma unroll
  for (int ng = 0; ng < 8; ++ng) acc[ng] = (f32x4_t){0.f, 0.f, 0.f, 0.f};

  for (int kb = 0; kb < 9; ++kb) {
    __syncthreads();
    // stage B slice: w1big[n][kb*128 + k]
#pragma unroll
    for (int it = 0; it < 8; ++it) {
      int flat = tid + it * 256;
      int row = flat >> 4, c8 = flat & 15;
      *(uint4*)(&Blds[row * LP + c8 * 8]) =
          *(const uint4*)(w1big + (size_t)row * KBIG + kb * 128 + c8 * 8);
    }
    __syncthreads();

    bf16x8_t af[4];
    if (kb < 8) {
      float a[4][8];
#pragma unroll
      for (int ks = 0; ks < 4; ++ks)
#pragma unroll
        for (int j = 0; j < 8; ++j) a[ks][j] = 0.f;
      if (myrow < NN) {
        int beg = off2[myrow * RRL + kb];
        int end = off2[myrow * RRL + kb + 1];
        int i = beg;
        unsigned sv = 0;
        float nrm = 0.f;
        if (i < end) {
          uint2 pp = ep1[i];
          sv = pp.x & 0xFFFFFFu;
          nrm = __uint_as_float(pp.y);
        }
        while (__ballot(i < end)) {
          unsigned sv2 = 0;
          float nrm2 = 0.f;
          if (i + 1 < end) {
            uint2 pp = ep1[i + 1];
            sv2 = pp.x & 0xFFFFFFu;
            nrm2 = __uint_as_float(pp.y);
          }
          const unsigned short* rp = x1b + (size_t)sv * HH + quad * 8;
          uint4 v0 = *(const uint4*)(rp);
          uint4 v1 = *(const uint4*)(rp + 32);
          uint4 v2 = *(const uint4*)(rp + 64);
          uint4 v3 = *(const uint4*)(rp + 96);
          acc8(a[0], v0, nrm);
          acc8(a[1], v1, nrm);
          acc8(a[2], v2, nrm);
          acc8(a[3], v3, nrm);
          ++i;
          sv = sv2;
          nrm = nrm2;
        }
      }
#pragma unroll
      for (int ks = 0; ks < 4; ++ks) {
        bf16x8_t f;
#pragma unroll
        for (int j = 0; j < 8; ++j) f[j] = (short)f2bf(a[ks][j]);
        af[ks] = f;
      }
    } else {
      const unsigned short* rp = x1b + (size_t)myrow * HH + quad * 8;
      af[0] = *(const bf16x8_t*)(rp);
      af[1] = *(const bf16x8_t*)(rp + 32);
      af[2] = *(const bf16x8_t*)(rp + 64);
      af[3] = *(const bf16x8_t*)(rp + 96);
    }

#pragma unroll
    for (int ks = 0; ks < 4; ++ks) {
      int ko = ks * 32 + quad * 8;
#pragma unroll
      for (int ng = 0; ng < 8; ++ng) {
        bf16x8_t bfr = *(const bf16x8_t*)(&Blds[(ng * 16 + l15) * LP + ko]);
        acc[ng] = __builtin_amdgcn_mfma_f32_16x16x32_bf16(af[ks], bfr, acc[ng], 0, 0, 0);
      }
    }
  }

  // epilogue: relu + bias, bf16 store
#pragma unroll
  for (int ng = 0; ng < 8; ++ng) {
    int col = ng * 16 + l15;
    float bv = bias1[col];
#pragma unroll
    for (int i2 = 0; i2 < 4; ++i2) {
      int m = row0 + w * 16 + quad * 4 + i2;
      float val = (m < NN) ? fmaxf(acc[ng][i2] + bv, 0.f) : 0.f;
      x2b[(size_t)m * HH + col] = f2bf(val);
    }
  }
}

// ---------------- layer-2 small MFMA GEMM (F=16): trans2 / out ----------------

__global__ __launch_bounds__(256) void gemm16_kernel(const unsigned short* __restrict__ A,
                                                     const unsigned short* __restrict__ Ball,
                                                     unsigned short* __restrict__ outb,
                                                     float* __restrict__ outf,
                                                     const float* __restrict__ bias,
                                                     int Mvalid) {
  constexpr int LP = 136;
  __shared__ unsigned short Alds[128 * LP];
  __shared__ unsigned short Blds[16 * LP];
  const int z = blockIdx.y;
  const int row0 = blockIdx.x * 128;
  const int tid = threadIdx.x;
  const unsigned short* B = Ball + (size_t)z * 128 * CC;

#pragma unroll
  for (int it = 0; it < 8; ++it) {
    int flat = tid + it * 256;
    int row = flat >> 4, c8 = flat & 15;
    *(uint4*)(&Alds[row * LP + c8 * 8]) =
        *(const uint4*)(A + ((size_t)(row0 + row)) * 128 + c8 * 8);
  }
  {
    int flat = tid;
    int row = flat >> 4, c8 = flat & 15;
    *(uint4*)(&Blds[row * LP + c8 * 8]) = *(const uint4*)(B + (size_t)row * 128 + c8 * 8);
  }
  __syncthreads();

  const int w = tid >> 6, lane = tid & 63;
  const int quad = lane >> 4, l15 = lane & 15;
  const int rb = w * 32;

  f32x4_t acc[2];
  acc[0] = (f32x4_t){0.f, 0.f, 0.f, 0.f};
  acc[1] = (f32x4_t){0.f, 0.f, 0.f, 0.f};
#pragma unroll
  for (int ks = 0; ks < 4; ++ks) {
    int ko = ks * 32 + quad * 8;
    bf16x8_t af[2], bfr;
    af[0] = *(const bf16x8_t*)(&Alds[(rb + l15) * LP + ko]);
    af[1] = *(const bf16x8_t*)(&Alds[(rb + 16 + l15) * LP + ko]);
    bfr = *(const bf16x8_t*)(&Blds[l15 * LP + ko]);
    acc[0] = __builtin_amdgcn_mfma_f32_16x16x32_bf16(af[0], bfr, acc[0], 0, 0, 0);
    acc[1] = __builtin_amdgcn_mfma_f32_16x16x32_bf16(af[1], bfr, acc[1], 0, 0, 0);
  }
  if (outf) {
#pragma unroll
    for (int rt = 0; rt < 2; ++rt) {
      float bv = bias[l15];
#pragma unroll
      for (int i = 0; i < 4; ++i) {
        int m = row0 + rb + rt * 16 + quad * 4 + i;
        if (m < Mvalid) outf[(size_t)m * CC + l15] = acc[rt][i] + bv;
      }
    }
  } else {
    unsigned short* ob = outb + (size_t)z * NP * CC;
#pragma unroll
    for (int rt = 0; rt < 2; ++rt)
#pragma unroll
      for (int i = 0; i < 4; ++i) {
        int m = row0 + rb + rt * 16 + quad * 4 + i;
        ob[(size_t)m * CC + l15] = f2bf(acc[rt][i]);
      }
  }
}

// ---------------- layer 2 gather: wave/dst, merged range, 8 slots x 8 lanes, 2x unroll ----------------

__global__ __launch_bounds__(256) void l2_seg_kernel(const int* __restrict__ off2,
                                                     const uint2* __restrict__ ep1,
                                                     const unsigned short* __restrict__ trans2,
                                                     float* __restrict__ outp) {
  int lane = threadIdx.x & 63;
  int n = blockIdx.x * 4 + (threadIdx.x >> 6);
  if (n >= NN) return;
  const int g = lane >> 3;
  const int t = lane & 7;
  float a0 = 0.f, a1 = 0.f;
  int beg = off2[n * RRL];
  int end = off2[n * RRL + RRL];
  int i = beg + g;
  uint2 p0 = {0u, 0u}, p1 = {0u, 0u};
  if (i < end) p0 = ep1[i];
  if (i + 8 < end) p1 = ep1[i + 8];
  while (i < end) {
    uint2 q0 = {0u, 0u}, q1 = {0u, 0u};
    if (i + 16 < end) q0 = ep1[i + 16];
    if (i + 24 < end) q1 = ep1[i + 24];
    unsigned s0 = p0.x & 0xFFFFFFu, z0 = p0.x >> 24;
    unsigned s1 = p1.x & 0xFFFFFFu, z1 = p1.x >> 24;
    unsigned int u0 =
        *(const unsigned int*)(trans2 + ((size_t)z0 * NP + s0) * CC + t * 2);
    unsigned int u1 =
        *(const unsigned int*)(trans2 + ((size_t)z1 * NP + s1) * CC + t * 2);
    float na = __uint_as_float(p0.y), nb = __uint_as_float(p1.y);
    a0 = fmaf(na, bflo(u0), a0);
    a1 = fmaf(na, bfhi(u0), a1);
    a0 = fmaf(nb, bflo(u1), a0);
    a1 = fmaf(nb, bfhi(u1), a1);
    i += 16;
    p0 = q0;
    p1 = q1;
  }
  a0 += __shfl_xor(a0, 8, 64);
  a0 += __shfl_xor(a0, 16, 64);
  a0 += __shfl_xor(a0, 32, 64);
  a1 += __shfl_xor(a1, 8, 64);
  a1 += __shfl_xor(a1, 16, 64);
  a1 += __shfl_xor(a1, 32, 64);
  if (g != 0) return;
  float2* o = (float2*)(outp + (size_t)n * CC) + t;
  float2 cv = *o;
  cv.x += a0;
  cv.y += a1;
  *o = cv;
}

// ---------------- launch ----------------

extern "C" void kernel_launch(void* const* d_in, const int* in_sizes, int n_in,
                              void* d_out, int out_size, void* d_ws, size_t ws_size,
                              hipStream_t stream) {
  const int* src = (const int*)d_in[0];
  const int* dst = (const int*)d_in[1];
  const int* h = (const int*)d_in[2];
  const int* r = (const int*)d_in[3];
  const float* norm = (const float*)d_in[4];
  const float* bases0 = (const float*)d_in[5];
  const float* wcomp0 = (const float*)d_in[6];
  const float* loop0 = (const float*)d_in[7];
  const float* bias0 = (const float*)d_in[8];
  const float* bases1 = (const float*)d_in[9];
  const float* wcomp1 = (const float*)d_in[10];
  const float* loop1 = (const float*)d_in[11];
  const float* bias1 = (const float*)d_in[12];
  const float* bases2 = (const float*)d_in[13];
  const float* wcomp2 = (const float*)d_in[14];
  const float* loop2 = (const float*)d_in[15];
  const float* bias2 = (const float*)d_in[16];
  float* out = (float*)d_out;

  char* p = (char*)d_ws;
  auto alloc = [&](size_t bytes) {
    char* q = p;
    p += (bytes + 255) & ~(size_t)255;
    return q;
  };
  unsigned short* x1b = (unsigned short*)alloc((size_t)NP * HH * 2);
  unsigned short* x2b = (unsigned short*)alloc((size_t)NP * HH * 2);
  unsigned short* trans2 = (unsigned short*)alloc((size_t)RRL * NP * CC * 2);
  unsigned short* w1big = (unsigned short*)alloc((size_t)HH * KBIG * 2);
  unsigned short* w2t = (unsigned short*)alloc((size_t)RRL * CC * HH * 2);
  unsigned short* loop2t = (unsigned short*)alloc((size_t)CC * HH * 2);
  uint2* ep0 = (uint2*)alloc((size_t)EE * 8);
  uint2* ep1 = (uint2*)alloc((size_t)EE * 8);
  int* off2 = (int*)alloc((size_t)(NT + 1) * 4);
  int* cur2 = (int*)alloc((size_t)NT * 4);
  int* cnt2 = (int*)alloc((size_t)NT * 4);
  int* partials = (int*)alloc(1024);
  int* pexcl = (int*)alloc(1024);
  // BIG: w0b [R][NP][128] bf16
  unsigned short* BIG = (unsigned short*)alloc((size_t)RRL * NP * HH * 2);

  // ---- counting sort of edges by (dst, rel) ----
  zero_kernel<<<(NT + 255) / 256, 256, 0, stream>>>(cnt2, NT);
  hist2_kernel<<<(EE + 255) / 256, 256, 0, stream>>>(r, dst, cnt2);
  scanA_kernel<<<NBLK_SCAN, 256, 0, stream>>>(cnt2, off2, partials);
  scanB_kernel<<<1, 256, 0, stream>>>(partials, pexcl);
  addC_kernel<<<NBLK_SCAN, 256, 0, stream>>>(off2, pexcl, cur2);
  scatter2_kernel<<<(EE + 255) / 256, 256, 0, stream>>>(r, dst, src, h, norm, cur2, ep0, ep1);

  // ---- compose bf16 weights ----
  compose_small_kernel<<<(HH * KBIG + RRL * CC * HH + CC * HH) / 256, 256, 0, stream>>>(
      wcomp1, bases1, loop1, wcomp2, bases2, loop2, w1big, w2t, loop2t);

  // ---- layer 0 ----
  w0b_build_kernel<<<(NN * 32) / 256, 256, 0, stream>>>(bases0, wcomp0, BIG);
  l0_seg_kernel<<<NP / 4, 256, 0, stream>>>(h, off2, ep0, BIG, loop0, bias0, x1b);

  // ---- layer 1: fused aggregate+transform ----
  l1_fused_kernel<<<NP / 64, 256, 0, stream>>>(off2, ep1, x1b, w1big, bias1, x2b);

  // ---- layer 2 ----
  gemm16_kernel<<<dim3(NP / 128, RRL), 256, 0, stream>>>(x2b, w2t, trans2, nullptr, nullptr,
                                                         NP);
  gemm16_kernel<<<dim3(NP / 128, 1), 256, 0, stream>>>(x2b, loop2t, nullptr, out, bias2, NN);
  l2_seg_kernel<<<(NN + 3) / 4, 256, 0, stream>>>(off2, ep1, trans2, out);
}

// Round 7
// 489.391 us; speedup vs baseline: 1.1314x; 1.1314x over previous
//
#include <hip/hip_runtime.h>

#define NN 50000
#define NP 50048            // padded rows (multiple of 128)
#define HH 128
#define CC 16
#define RRL 8
#define BB 4
#define EE 800000
#define NT (RRL * NN)       // 400000 (dst,rel) buckets, key = dst*8+rel
#define SCAN_CHUNK 2048
#define NBLK_SCAN ((NT + SCAN_CHUNK - 1) / SCAN_CHUNK)  // 196
#define KBIG 1152           // 8*128 (relations) + 128 (self-loop)

typedef short bf16x8_t __attribute__((ext_vector_type(8)));
typedef float f32x4_t __attribute__((ext_vector_type(4)));

__device__ __forceinline__ unsigned short f2bf(float f) {
  unsigned int x = __float_as_uint(f);
  unsigned int r = x + 0x7fffu + ((x >> 16) & 1u);
  return (unsigned short)(r >> 16);
}
__device__ __forceinline__ float bflo(unsigned int u) { return __uint_as_float(u << 16); }
__device__ __forceinline__ float bfhi(unsigned int u) {
  return __uint_as_float(u & 0xffff0000u);
}
__device__ __forceinline__ void acc8(float* a, uint4 v, float nrm) {
  a[0] = fmaf(nrm, bflo(v.x), a[0]);
  a[1] = fmaf(nrm, bfhi(v.x), a[1]);
  a[2] = fmaf(nrm, bflo(v.y), a[2]);
  a[3] = fmaf(nrm, bfhi(v.y), a[3]);
  a[4] = fmaf(nrm, bflo(v.z), a[4]);
  a[5] = fmaf(nrm, bfhi(v.z), a[5]);
  a[6] = fmaf(nrm, bflo(v.w), a[6]);
  a[7] = fmaf(nrm, bfhi(v.w), a[7]);
}

// ---------------- utility ----------------

__global__ __launch_bounds__(256) void zero_kernel(int* p, int n) {
  int i = blockIdx.x * 256 + threadIdx.x;
  if (i < n) p[i] = 0;
}

// ---------------- counting sort by key = dst*8 + rel ----------------

__global__ __launch_bounds__(256) void hist2_kernel(const int* __restrict__ r,
                                                    const int* __restrict__ dst,
                                                    int* __restrict__ cnt) {
  int e = blockIdx.x * 256 + threadIdx.x;
  if (e < EE) atomicAdd(&cnt[dst[e] * RRL + r[e]], 1);
}

__global__ __launch_bounds__(256) void scanA_kernel(const int* __restrict__ cnt,
                                                    int* __restrict__ off,
                                                    int* __restrict__ partials) {
  __shared__ int sums[256];
  int tid = threadIdx.x;
  int base = blockIdx.x * SCAN_CHUNK + tid * 8;
  int v[8];
  int s = 0;
#pragma unroll
  for (int j = 0; j < 8; ++j) {
    int idx = base + j;
    v[j] = (idx < NT) ? cnt[idx] : 0;
    s += v[j];
  }
  sums[tid] = s;
  __syncthreads();
  for (int o = 1; o < 256; o <<= 1) {
    int t = (tid >= o) ? sums[tid - o] : 0;
    __syncthreads();
    sums[tid] += t;
    __syncthreads();
  }
  int run = sums[tid] - s;
#pragma unroll
  for (int j = 0; j < 8; ++j) {
    int idx = base + j;
    if (idx < NT) off[idx] = run;
    run += v[j];
  }
  if (tid == 255) partials[blockIdx.x] = sums[255];
}

__global__ __launch_bounds__(256) void scanB_kernel(const int* __restrict__ partials,
                                                    int* __restrict__ pexcl) {
  __shared__ int sums[256];
  int tid = threadIdx.x;
  int p = (tid < NBLK_SCAN) ? partials[tid] : 0;
  sums[tid] = p;
  __syncthreads();
  for (int o = 1; o < 256; o <<= 1) {
    int t = (tid >= o) ? sums[tid - o] : 0;
    __syncthreads();
    sums[tid] += t;
    __syncthreads();
  }
  if (tid < NBLK_SCAN) pexcl[tid] = sums[tid] - p;
}

__global__ __launch_bounds__(256) void addC_kernel(int* __restrict__ off,
                                                   const int* __restrict__ pexcl,
                                                   int* __restrict__ cur) {
  int tid = threadIdx.x;
  int add = pexcl[blockIdx.x];
  int base = blockIdx.x * SCAN_CHUNK + tid * 8;
#pragma unroll
  for (int j = 0; j < 8; ++j) {
    int idx = base + j;
    if (idx < NT) {
      int v = off[idx] + add;
      off[idx] = v;
      cur[idx] = v;
    }
  }
  if (blockIdx.x == 0 && tid == 0) off[NT] = EE;
}

// payloads: ep0 = (w0b row index = z*NP + h[src], norm bits)
//           ep1 = (src | z<<24, norm bits)
__global__ __launch_bounds__(256) void scatter2_kernel(
    const int* __restrict__ r, const int* __restrict__ dst, const int* __restrict__ src,
    const int* __restrict__ h, const float* __restrict__ norm, int* __restrict__ cur,
    uint2* __restrict__ ep0, uint2* __restrict__ ep1) {
  int e = blockIdx.x * 256 + threadIdx.x;
  if (e >= EE) return;
  int z = r[e];
  int key = dst[e] * RRL + z;
  int pos = atomicAdd(&cur[key], 1);
  int sv = src[e];
  unsigned int nb = __float_as_uint(norm[e]);
  uint2 a, b;
  a.x = (unsigned)(z * NP + h[sv]);
  a.y = nb;
  b.x = (unsigned)sv | ((unsigned)z << 24);
  b.y = nb;
  ep0[pos] = a;
  ep1[pos] = b;
}

// ---------------- compose weights (bf16) ----------------
// w1big[n][k], k in [0,1024): rel z=k>>7; k in [1024,1152): loop1. Layout row-major [128][1152].
// w2t[z][n16][k128], loop2t[n16][k128].

__global__ __launch_bounds__(256) void compose_small_kernel(
    const float* __restrict__ wcomp1, const float* __restrict__ bases1,
    const float* __restrict__ loop1, const float* __restrict__ wcomp2,
    const float* __restrict__ bases2, const float* __restrict__ loop2,
    unsigned short* __restrict__ w1big, unsigned short* __restrict__ w2t,
    unsigned short* __restrict__ loop2t) {
  int idx = blockIdx.x * 256 + threadIdx.x;
  if (idx < HH * KBIG) {  // w1big[n][k]
    int n = idx / KBIG, k = idx - n * KBIG;
    float a;
    if (k < 1024) {
      int z = k >> 7, kk = k & 127;
      a = 0.f;
#pragma unroll
      for (int b = 0; b < BB; ++b)
        a += wcomp1[z * BB + b] * bases1[((size_t)b * HH + kk) * HH + n];
    } else {
      int kk = k - 1024;
      a = loop1[kk * HH + n];
    }
    w1big[idx] = f2bf(a);
    return;
  }
  int j = idx - HH * KBIG;
  if (j < RRL * CC * HH) {  // w2t[z][n][k]
    int z = j >> 11;
    int rem = j & 2047;
    int n = rem >> 7, k = rem & 127;
    float a = 0.f;
#pragma unroll
    for (int b = 0; b < BB; ++b)
      a += wcomp2[z * BB + b] * bases2[((size_t)b * HH + k) * CC + n];
    w2t[j] = f2bf(a);
    return;
  }
  j -= RRL * CC * HH;
  if (j < CC * HH) {  // loop2t[n][k]
    int n = j >> 7, k = j & 127;
    loop2t[j] = f2bf(loop2[k * CC + n]);
  }
}

// ---------------- w0 bf16 table: w0b[z][m][f] ----------------

__global__ __launch_bounds__(256) void w0b_build_kernel(const float* __restrict__ bases0,
                                                        const float* __restrict__ wcomp0,
                                                        unsigned short* __restrict__ w0b) {
  int idx = blockIdx.x * 256 + threadIdx.x;  // m*32 + c
  int m = idx >> 5, c = idx & 31;
  if (m >= NN) return;
  float4 b0 = ((const float4*)(bases0 + ((size_t)0 * NN + m) * HH))[c];
  float4 b1 = ((const float4*)(bases0 + ((size_t)1 * NN + m) * HH))[c];
  float4 b2 = ((const float4*)(bases0 + ((size_t)2 * NN + m) * HH))[c];
  float4 b3 = ((const float4*)(bases0 + ((size_t)3 * NN + m) * HH))[c];
#pragma unroll
  for (int z = 0; z < RRL; ++z) {
    float c0 = wcomp0[z * BB + 0], c1 = wcomp0[z * BB + 1];
    float c2 = wcomp0[z * BB + 2], c3 = wcomp0[z * BB + 3];
    float vx = c0 * b0.x + c1 * b1.x + c2 * b2.x + c3 * b3.x;
    float vy = c0 * b0.y + c1 * b1.y + c2 * b2.y + c3 * b3.y;
    float vz = c0 * b0.z + c1 * b1.z + c2 * b2.z + c3 * b3.z;
    float vw = c0 * b0.w + c1 * b1.w + c2 * b2.w + c3 * b3.w;
    uint2 pk;
    pk.x = ((unsigned)f2bf(vy) << 16) | f2bf(vx);
    pk.y = ((unsigned)f2bf(vw) << 16) | f2bf(vz);
    ((uint2*)(w0b + ((size_t)z * NP + m) * HH))[c] = pk;
  }
}

// ---------------- layer 0: wave/dst, merged range, 4 slots x 16 lanes, 2x unroll ----------------

__global__ __launch_bounds__(256) void l0_seg_kernel(
    const int* __restrict__ h, const int* __restrict__ off2, const uint2* __restrict__ ep0,
    const unsigned short* __restrict__ w0b, const float* __restrict__ loop0,
    const float* __restrict__ bias0, unsigned short* __restrict__ x1b) {
  int lane = threadIdx.x & 63;
  int n = blockIdx.x * 4 + (threadIdx.x >> 6);
  if (n >= NP) return;
  const int g = lane >> 4;
  const int t = lane & 15;
  float acc[8];
#pragma unroll
  for (int j = 0; j < 8; ++j) acc[j] = 0.f;

  if (n < NN) {
    int beg = off2[n * RRL];
    int end = off2[n * RRL + RRL];
    int i = beg + g;
    uint2 p0 = {0u, 0u}, p1 = {0u, 0u};
    if (i < end) p0 = ep0[i];
    if (i + 4 < end) p1 = ep0[i + 4];
    while (i < end) {
      uint2 q0 = {0u, 0u}, q1 = {0u, 0u};
      if (i + 8 < end) q0 = ep0[i + 8];
      if (i + 12 < end) q1 = ep0[i + 12];
      uint4 va = *(const uint4*)(w0b + (size_t)p0.x * HH + t * 8);
      uint4 vb = *(const uint4*)(w0b + (size_t)p1.x * HH + t * 8);
      float na = __uint_as_float(p0.y), nb = __uint_as_float(p1.y);
      acc8(acc, va, na);
      acc8(acc, vb, nb);
      i += 8;
      p0 = q0;
      p1 = q1;
    }
  }
#pragma unroll
  for (int j = 0; j < 8; ++j) {
    acc[j] += __shfl_xor(acc[j], 16, 64);
    acc[j] += __shfl_xor(acc[j], 32, 64);
  }
  if (g != 0) return;
  uint4 o = {0u, 0u, 0u, 0u};
  if (n < NN) {
    int hn = h[n];
    float4 l0v = ((const float4*)(loop0 + (size_t)hn * HH))[t * 2];
    float4 l1v = ((const float4*)(loop0 + (size_t)hn * HH))[t * 2 + 1];
    float4 b0v = ((const float4*)bias0)[t * 2];
    float4 b1v = ((const float4*)bias0)[t * 2 + 1];
    float e0 = fmaxf(acc[0] + l0v.x + b0v.x, 0.f);
    float e1 = fmaxf(acc[1] + l0v.y + b0v.y, 0.f);
    float e2 = fmaxf(acc[2] + l0v.z + b0v.z, 0.f);
    float e3 = fmaxf(acc[3] + l0v.w + b0v.w, 0.f);
    float e4 = fmaxf(acc[4] + l1v.x + b1v.x, 0.f);
    float e5 = fmaxf(acc[5] + l1v.y + b1v.y, 0.f);
    float e6 = fmaxf(acc[6] + l1v.z + b1v.z, 0.f);
    float e7 = fmaxf(acc[7] + l1v.w + b1v.w, 0.f);
    o.x = ((unsigned)f2bf(e1) << 16) | f2bf(e0);
    o.y = ((unsigned)f2bf(e3) << 16) | f2bf(e2);
    o.z = ((unsigned)f2bf(e5) << 16) | f2bf(e4);
    o.w = ((unsigned)f2bf(e7) << 16) | f2bf(e6);
  }
  *(uint4*)(x1b + (size_t)n * HH + t * 8) = o;
}

// ---------------- layer 1 aggregate: one 16-lane group per (dst,rel) bucket ----------------
// bucket gid = dst*8+rel == off2 index. 16 lanes cover the 256B x1b row (uint4 each).
// No cross-lane reduction. 2x unrolled prefetch -> 8 row-loads in flight per wave.

__global__ __launch_bounds__(256) void l1_agg_kernel(const int* __restrict__ off2,
                                                     const uint2* __restrict__ ep1,
                                                     const unsigned short* __restrict__ x1b,
                                                     unsigned short* __restrict__ AGG) {
  int tid = threadIdx.x;
  int gid = blockIdx.x * 16 + (tid >> 4);  // bucket index
  int l = tid & 15;
  int n = gid >> 3, z = gid & 7;
  if (n >= NP) return;
  unsigned short* orow = AGG + (size_t)n * 1024 + z * 128 + l * 8;
  if (n >= NN) {
    *(uint4*)orow = (uint4){0u, 0u, 0u, 0u};
    return;
  }
  int beg = off2[gid];
  int end = off2[gid + 1];
  float a[8];
#pragma unroll
  for (int j = 0; j < 8; ++j) a[j] = 0.f;

  int i = beg;
  uint2 p0 = {0u, 0u}, p1 = {0u, 0u};
  if (i < end) p0 = ep1[i];
  if (i + 1 < end) p1 = ep1[i + 1];
  while (i < end) {
    uint2 q0 = {0u, 0u}, q1 = {0u, 0u};
    if (i + 2 < end) q0 = ep1[i + 2];
    if (i + 3 < end) q1 = ep1[i + 3];
    unsigned s0 = p0.x & 0xFFFFFFu, s1 = p1.x & 0xFFFFFFu;
    uint4 v0 = *(const uint4*)(x1b + (size_t)s0 * HH + l * 8);
    uint4 v1 = *(const uint4*)(x1b + (size_t)s1 * HH + l * 8);
    float n0 = __uint_as_float(p0.y), n1 = __uint_as_float(p1.y);
    acc8(a, v0, n0);
    acc8(a, v1, n1);
    i += 2;
    p0 = q0;
    p1 = q1;
  }
  uint4 o;
  o.x = ((unsigned)f2bf(a[1]) << 16) | f2bf(a[0]);
  o.y = ((unsigned)f2bf(a[3]) << 16) | f2bf(a[2]);
  o.z = ((unsigned)f2bf(a[5]) << 16) | f2bf(a[4]);
  o.w = ((unsigned)f2bf(a[7]) << 16) | f2bf(a[6]);
  *(uint4*)orow = o;
}

// ---------------- K=1152 MFMA GEMM: x2b = relu([AGG | x1b] @ w1big^T + bias1) ----------------

__global__ __launch_bounds__(256) void gemm_k1152_kernel(
    const unsigned short* __restrict__ AGG, const unsigned short* __restrict__ x1b,
    const unsigned short* __restrict__ w1big, const float* __restrict__ bias1,
    unsigned short* __restrict__ x2b) {
  constexpr int LP = 136;
  __shared__ unsigned short Alds[64 * LP];
  __shared__ unsigned short Blds[128 * LP];
  const int row0 = blockIdx.x * 64;
  const int tid = threadIdx.x;
  const int w = tid >> 6, lane = tid & 63;
  const int quad = lane >> 4, l15 = lane & 15;
  const int rb = (w >> 1) * 32;
  const int cb = (w & 1) * 64;

  f32x4_t acc[2][4];
#pragma unroll
  for (int rt = 0; rt < 2; ++rt)
#pragma unroll
    for (int ct = 0; ct < 4; ++ct) acc[rt][ct] = (f32x4_t){0.f, 0.f, 0.f, 0.f};

  for (int kb = 0; kb < 9; ++kb) {
    if (kb) __syncthreads();
    // A tile 64 rows x 128 k
#pragma unroll
    for (int it = 0; it < 4; ++it) {
      int flat = tid + it * 256;
      int row = flat >> 4, c8 = flat & 15;
      const unsigned short* srcp =
          (kb < 8) ? AGG + (size_t)(row0 + row) * 1024 + kb * 128 + c8 * 8
                   : x1b + (size_t)(row0 + row) * 128 + c8 * 8;
      *(uint4*)(&Alds[row * LP + c8 * 8]) = *(const uint4*)srcp;
    }
    // B tile 128 n x 128 k
#pragma unroll
    for (int it = 0; it < 8; ++it) {
      int flat = tid + it * 256;
      int row = flat >> 4, c8 = flat & 15;
      *(uint4*)(&Blds[row * LP + c8 * 8]) =
          *(const uint4*)(w1big + (size_t)row * KBIG + kb * 128 + c8 * 8);
    }
    __syncthreads();
#pragma unroll
    for (int ks = 0; ks < 4; ++ks) {
      int ko = ks * 32 + quad * 8;
      bf16x8_t af[2], bfr[4];
#pragma unroll
      for (int rt = 0; rt < 2; ++rt)
        af[rt] = *(const bf16x8_t*)(&Alds[(rb + rt * 16 + l15) * LP + ko]);
#pragma unroll
      for (int ct = 0; ct < 4; ++ct)
        bfr[ct] = *(const bf16x8_t*)(&Blds[(cb + ct * 16 + l15) * LP + ko]);
#pragma unroll
      for (int rt = 0; rt < 2; ++rt)
#pragma unroll
        for (int ct = 0; ct < 4; ++ct)
          acc[rt][ct] =
              __builtin_amdgcn_mfma_f32_16x16x32_bf16(af[rt], bfr[ct], acc[rt][ct], 0, 0, 0);
    }
  }
#pragma unroll
  for (int rt = 0; rt < 2; ++rt)
#pragma unroll
    for (int ct = 0; ct < 4; ++ct) {
      int n = cb + ct * 16 + l15;
      float bv = bias1[n];
#pragma unroll
      for (int i = 0; i < 4; ++i) {
        int m = row0 + rb + rt * 16 + quad * 4 + i;
        float val = (m < NN) ? fmaxf(acc[rt][ct][i] + bv, 0.f) : 0.f;
        x2b[(size_t)m * HH + n] = f2bf(val);
      }
    }
}

// ---------------- layer-2 small MFMA GEMM (F=16): trans2 / out ----------------

__global__ __launch_bounds__(256) void gemm16_kernel(const unsigned short* __restrict__ A,
                                                     const unsigned short* __restrict__ Ball,
                                                     unsigned short* __restrict__ outb,
                                                     float* __restrict__ outf,
                                                     const float* __restrict__ bias,
                                                     int Mvalid) {
  constexpr int LP = 136;
  __shared__ unsigned short Alds[128 * LP];
  __shared__ unsigned short Blds[16 * LP];
  const int z = blockIdx.y;
  const int row0 = blockIdx.x * 128;
  const int tid = threadIdx.x;
  const unsigned short* B = Ball + (size_t)z * 128 * CC;

#pragma unroll
  for (int it = 0; it < 8; ++it) {
    int flat = tid + it * 256;
    int row = flat >> 4, c8 = flat & 15;
    *(uint4*)(&Alds[row * LP + c8 * 8]) =
        *(const uint4*)(A + ((size_t)(row0 + row)) * 128 + c8 * 8);
  }
  {
    int flat = tid;
    int row = flat >> 4, c8 = flat & 15;
    *(uint4*)(&Blds[row * LP + c8 * 8]) = *(const uint4*)(B + (size_t)row * 128 + c8 * 8);
  }
  __syncthreads();

  const int w = tid >> 6, lane = tid & 63;
  const int quad = lane >> 4, l15 = lane & 15;
  const int rb = w * 32;

  f32x4_t acc[2];
  acc[0] = (f32x4_t){0.f, 0.f, 0.f, 0.f};
  acc[1] = (f32x4_t){0.f, 0.f, 0.f, 0.f};
#pragma unroll
  for (int ks = 0; ks < 4; ++ks) {
    int ko = ks * 32 + quad * 8;
    bf16x8_t af[2], bfr;
    af[0] = *(const bf16x8_t*)(&Alds[(rb + l15) * LP + ko]);
    af[1] = *(const bf16x8_t*)(&Alds[(rb + 16 + l15) * LP + ko]);
    bfr = *(const bf16x8_t*)(&Blds[l15 * LP + ko]);
    acc[0] = __builtin_amdgcn_mfma_f32_16x16x32_bf16(af[0], bfr, acc[0], 0, 0, 0);
    acc[1] = __builtin_amdgcn_mfma_f32_16x16x32_bf16(af[1], bfr, acc[1], 0, 0, 0);
  }
  if (outf) {
#pragma unroll
    for (int rt = 0; rt < 2; ++rt) {
      float bv = bias[l15];
#pragma unroll
      for (int i = 0; i < 4; ++i) {
        int m = row0 + rb + rt * 16 + quad * 4 + i;
        if (m < Mvalid) outf[(size_t)m * CC + l15] = acc[rt][i] + bv;
      }
    }
  } else {
    unsigned short* ob = outb + (size_t)z * NP * CC;
#pragma unroll
    for (int rt = 0; rt < 2; ++rt)
#pragma unroll
      for (int i = 0; i < 4; ++i) {
        int m = row0 + rb + rt * 16 + quad * 4 + i;
        ob[(size_t)m * CC + l15] = f2bf(acc[rt][i]);
      }
  }
}

// ---------------- layer 2 gather: wave/dst, merged range, 8 slots x 8 lanes, 2x unroll ----------------

__global__ __launch_bounds__(256) void l2_seg_kernel(const int* __restrict__ off2,
                                                     const uint2* __restrict__ ep1,
                                                     const unsigned short* __restrict__ trans2,
                                                     float* __restrict__ outp) {
  int lane = threadIdx.x & 63;
  int n = blockIdx.x * 4 + (threadIdx.x >> 6);
  if (n >= NN) return;
  const int g = lane >> 3;
  const int t = lane & 7;
  float a0 = 0.f, a1 = 0.f;
  int beg = off2[n * RRL];
  int end = off2[n * RRL + RRL];
  int i = beg + g;
  uint2 p0 = {0u, 0u}, p1 = {0u, 0u};
  if (i < end) p0 = ep1[i];
  if (i + 8 < end) p1 = ep1[i + 8];
  while (i < end) {
    uint2 q0 = {0u, 0u}, q1 = {0u, 0u};
    if (i + 16 < end) q0 = ep1[i + 16];
    if (i + 24 < end) q1 = ep1[i + 24];
    unsigned s0 = p0.x & 0xFFFFFFu, z0 = p0.x >> 24;
    unsigned s1 = p1.x & 0xFFFFFFu, z1 = p1.x >> 24;
    unsigned int u0 =
        *(const unsigned int*)(trans2 + ((size_t)z0 * NP + s0) * CC + t * 2);
    unsigned int u1 =
        *(const unsigned int*)(trans2 + ((size_t)z1 * NP + s1) * CC + t * 2);
    float na = __uint_as_float(p0.y), nb = __uint_as_float(p1.y);
    a0 = fmaf(na, bflo(u0), a0);
    a1 = fmaf(na, bfhi(u0), a1);
    a0 = fmaf(nb, bflo(u1), a0);
    a1 = fmaf(nb, bfhi(u1), a1);
    i += 16;
    p0 = q0;
    p1 = q1;
  }
  a0 += __shfl_xor(a0, 8, 64);
  a0 += __shfl_xor(a0, 16, 64);
  a0 += __shfl_xor(a0, 32, 64);
  a1 += __shfl_xor(a1, 8, 64);
  a1 += __shfl_xor(a1, 16, 64);
  a1 += __shfl_xor(a1, 32, 64);
  if (g != 0) return;
  float2* o = (float2*)(outp + (size_t)n * CC) + t;
  float2 cv = *o;
  cv.x += a0;
  cv.y += a1;
  *o = cv;
}

// ---------------- launch ----------------

extern "C" void kernel_launch(void* const* d_in, const int* in_sizes, int n_in,
                              void* d_out, int out_size, void* d_ws, size_t ws_size,
                              hipStream_t stream) {
  const int* src = (const int*)d_in[0];
  const int* dst = (const int*)d_in[1];
  const int* h = (const int*)d_in[2];
  const int* r = (const int*)d_in[3];
  const float* norm = (const float*)d_in[4];
  const float* bases0 = (const float*)d_in[5];
  const float* wcomp0 = (const float*)d_in[6];
  const float* loop0 = (const float*)d_in[7];
  const float* bias0 = (const float*)d_in[8];
  const float* bases1 = (const float*)d_in[9];
  const float* wcomp1 = (const float*)d_in[10];
  const float* loop1 = (const float*)d_in[11];
  const float* bias1 = (const float*)d_in[12];
  const float* bases2 = (const float*)d_in[13];
  const float* wcomp2 = (const float*)d_in[14];
  const float* loop2 = (const float*)d_in[15];
  const float* bias2 = (const float*)d_in[16];
  float* out = (float*)d_out;

  char* p = (char*)d_ws;
  auto alloc = [&](size_t bytes) {
    char* q = p;
    p += (bytes + 255) & ~(size_t)255;
    return q;
  };
  unsigned short* x1b = (unsigned short*)alloc((size_t)NP * HH * 2);
  unsigned short* x2b = (unsigned short*)alloc((size_t)NP * HH * 2);
  unsigned short* trans2 = (unsigned short*)alloc((size_t)RRL * NP * CC * 2);
  unsigned short* w1big = (unsigned short*)alloc((size_t)HH * KBIG * 2);
  unsigned short* w2t = (unsigned short*)alloc((size_t)RRL * CC * HH * 2);
  unsigned short* loop2t = (unsigned short*)alloc((size_t)CC * HH * 2);
  uint2* ep0 = (uint2*)alloc((size_t)EE * 8);
  uint2* ep1 = (uint2*)alloc((size_t)EE * 8);
  int* off2 = (int*)alloc((size_t)(NT + 1) * 4);
  int* cur2 = (int*)alloc((size_t)NT * 4);
  int* cnt2 = (int*)alloc((size_t)NT * 4);
  int* partials = (int*)alloc(1024);
  int* pexcl = (int*)alloc(1024);
  // BIG: w0b [R][NP][128] bf16 during layer 0, then reused as AGG [NP][1024] bf16
  unsigned short* BIG = (unsigned short*)alloc((size_t)RRL * NP * HH * 2);

  // ---- counting sort of edges by (dst, rel) ----
  zero_kernel<<<(NT + 255) / 256, 256, 0, stream>>>(cnt2, NT);
  hist2_kernel<<<(EE + 255) / 256, 256, 0, stream>>>(r, dst, cnt2);
  scanA_kernel<<<NBLK_SCAN, 256, 0, stream>>>(cnt2, off2, partials);
  scanB_kernel<<<1, 256, 0, stream>>>(partials, pexcl);
  addC_kernel<<<NBLK_SCAN, 256, 0, stream>>>(off2, pexcl, cur2);
  scatter2_kernel<<<(EE + 255) / 256, 256, 0, stream>>>(r, dst, src, h, norm, cur2, ep0, ep1);

  // ---- compose bf16 weights ----
  compose_small_kernel<<<(HH * KBIG + RRL * CC * HH + CC * HH) / 256, 256, 0, stream>>>(
      wcomp1, bases1, loop1, wcomp2, bases2, loop2, w1big, w2t, loop2t);

  // ---- layer 0 ----
  w0b_build_kernel<<<(NN * 32) / 256, 256, 0, stream>>>(bases0, wcomp0, BIG);
  l0_seg_kernel<<<NP / 4, 256, 0, stream>>>(h, off2, ep0, BIG, loop0, bias0, x1b);

  // ---- layer 1: bucket-parallel aggregate (AGG overwrites w0b), then K=1152 GEMM ----
  l1_agg_kernel<<<NP * 8 / 16, 256, 0, stream>>>(off2, ep1, x1b, BIG);
  gemm_k1152_kernel<<<NP / 64, 256, 0, stream>>>(BIG, x1b, w1big, bias1, x2b);

  // ---- layer 2 ----
  gemm16_kernel<<<dim3(NP / 128, RRL), 256, 0, stream>>>(x2b, w2t, trans2, nullptr, nullptr,
                                                         NP);
  gemm16_kernel<<<dim3(NP / 128, 1), 256, 0, stream>>>(x2b, loop2t, nullptr, out, bias2, NN);
  l2_seg_kernel<<<(NN + 3) / 4, 256, 0, stream>>>(off2, ep1, trans2, out);
}